// Round 14
// baseline (155.106 us; speedup 1.0000x reference)
//
#include <hip/hip_runtime.h>

typedef float f32x4 __attribute__((ext_vector_type(4)));
typedef __bf16 bf16x8 __attribute__((ext_vector_type(8)));

__device__ __forceinline__ unsigned short f2bf(float f) {
  unsigned u = __builtin_bit_cast(unsigned, f);
  u = (u + 0x7FFFu + ((u >> 16) & 1u)) >> 16;
  return (unsigned short)u;
}

__device__ __forceinline__ f32x4 MFMA16(uint4 a, uint4 b, f32x4 c) {
  return __builtin_amdgcn_mfma_f32_16x16x32_bf16(
      __builtin_bit_cast(bf16x8, a), __builtin_bit_cast(bf16x8, b), c, 0, 0, 0);
}

__device__ __forceinline__ unsigned cvtpk(float lo, float hi) {
  unsigned r;
  asm("v_cvt_pk_bf16_f32 %0, %1, %2" : "=v"(r) : "v"(lo), "v"(hi));
  return r;
}

__device__ __forceinline__ float actf(float p) {
  p = fminf(fmaxf(p, -15.f), 15.f);
  float ep = __expf(p);
  float e2 = ep * ep;
  float sg = ep * __builtin_amdgcn_rcpf(1.f + ep);
  float th = (e2 - 1.f) * __builtin_amdgcn_rcpf(e2 + 1.f);
  return th * sg;
}

// ---------------- weight prep: unpadded bf16 images (contiguous 81920 sh) ----
// wd2:  [8 kc][128 o][32 kl]      = 32768 elems
// wrs2: [3 p][4 kk][128 o][32 kl] = 49152 elems
__global__ void wn_prep(const float* __restrict__ wd, const float* __restrict__ wres,
                        const float* __restrict__ wskip, unsigned short* __restrict__ ws16) {
  int g = blockIdx.x * 256 + threadIdx.x;   // grid 320*256 = 81920 exactly
  if (g < 32768) {
    int kc = g >> 12, rem = g & 4095;
    int o = rem >> 5, kl = rem & 31;
    int k = kc * 32 + kl;
    int tap = k >> 7, i = k & 127;
    ws16[g] = f2bf(wd[(o << 8) + (i << 1) + tap]);  // w_dil (128,128,2)
  } else {
    int g2 = g - 32768;
    int pkk = g2 >> 12;           // 0..11
    int rem = g2 & 4095;
    int o = rem >> 5, kl = rem & 31;
    int p = pkk >> 2, kk = pkk & 3;
    int k = kk * 32 + kl;
    float v = (p == 0) ? wres[o * 128 + k] : wskip[((p - 1) * 128 + o) * 128 + k];
    ws16[32768 + g2] = f2bf(v);
  }
}

// ---------------- persistent wave-autonomous main kernel ----------------
// 256 blocks x 512 threads; 160KB LDS holds ALL weights (preload once, ONE
// barrier total). Each of the 8 waves independently processes 16-column
// t-slices: full M=128 per slice, A-operands from LDS, x direct from global,
// stage1->stage2 transpose fully in-register (cvt_pk_bf16 + ds_bpermute).
// Zero barriers in steady state; __launch_bounds__(512,2) -> 256-reg budget.
__global__ __launch_bounds__(512, 2) void wn_main(
    const float* __restrict__ x,
    const float* __restrict__ bres_g,
    const float* __restrict__ bskip_g,
    const unsigned short* __restrict__ wimg,   // 81920 sh
    float* __restrict__ out,
    float* __restrict__ skipo) {
  extern __shared__ unsigned short lds[];
  {
    const uint4* src = (const uint4*)wimg;
    uint4* dst = (uint4*)lds;
    int t = threadIdx.x;
#pragma unroll
    for (int i = 0; i < 20; ++i) dst[t + i * 512] = src[t + i * 512];
  }
  __syncthreads();   // the only barrier in the kernel
  const unsigned short* wdl = lds;            // [8][128][32]
  const unsigned short* wrl = lds + 32768;    // [12][128][32]

  const int bid = blockIdx.x;                 // 0..255, 1 block/CU (160KB LDS)
  const int tid = threadIdx.x;
  const int wv = tid >> 6;
  const int lane = tid & 63;
  const int l15 = lane & 15, lhi = lane >> 4;
  const int b = bid & 7;                      // XCD-pinned batch
  const int u = ((bid >> 3) << 3) + wv;       // 0..255: per-batch wave id

  const float* xb = x + (size_t)b * (128 * 16384);
  const int permA = ((((lhi & 1) * 2) * 16 + l15) << 2);  // bpermute byte addr
  const int permB = permA + 64;                            // +16 lanes
  const bool loSel = (lhi < 2);

#pragma unroll 1
  for (int it = 0; it < 4; ++it) {
    const int tsl = u + (it << 8);       // t-slice id 0..991 (x16 cols)
    if (tsl >= 992) break;
    const int t0w = tsl << 4;

    // ---- stage 1: pre[o][t16] = [W0|W1] @ [x(t);x(t+512)], K=256 ----
    f32x4 acc[8];
#pragma unroll
    for (int i = 0; i < 8; ++i) acc[i] = (f32x4){0.f, 0.f, 0.f, 0.f};

#pragma unroll 2
    for (int kc = 0; kc < 8; ++kc) {
      const float* xq = xb + (size_t)((kc & 3) * 32 + lhi * 8) * 16384
                      + t0w + ((kc >> 2) << 9) + l15;
      float xf[8];
#pragma unroll
      for (int j = 0; j < 8; ++j) xf[j] = xq[(size_t)j * 16384];
      bf16x8 tv;
#pragma unroll
      for (int j = 0; j < 8; ++j) tv[j] = (__bf16)xf[j];
      const uint4 bfr = __builtin_bit_cast(uint4, tv);
      const unsigned short* wb0 = wdl + (kc << 12) + lhi * 8;
#pragma unroll
      for (int mi = 0; mi < 8; ++mi) {
        uint4 af = *(const uint4*)(wb0 + (mi * 16 + l15) * 32);
        acc[mi] = MFMA16(af, bfr, acc[mi]);
      }
    }

    // ---- activation + pack to bf16 pairs ----
    unsigned a01[8], a23[8];
#pragma unroll
    for (int m = 0; m < 8; ++m) {
      a01[m] = cvtpk(actf(acc[m][0]), actf(acc[m][1]));
      a23[m] = cvtpk(actf(acc[m][2]), actf(acc[m][3]));
    }

    // ---- in-register transpose: B-frags for stage 2 (wave-internal) ----
    // dest lane(lhi,l15) elem j: act[k'=kk*32+lhi*8+j][t=l15]
    uint4 bfr2[4];
#pragma unroll
    for (int kk = 0; kk < 4; ++kk) {
      int qa01 = (int)a01[2 * kk],     qa23 = (int)a23[2 * kk];
      int qb01 = (int)a01[2 * kk + 1], qb23 = (int)a23[2 * kk + 1];
      int e0a = __builtin_amdgcn_ds_bpermute(permA, qa01);
      int e0b = __builtin_amdgcn_ds_bpermute(permA, qb01);
      int e1a = __builtin_amdgcn_ds_bpermute(permA, qa23);
      int e1b = __builtin_amdgcn_ds_bpermute(permA, qb23);
      int e2a = __builtin_amdgcn_ds_bpermute(permB, qa01);
      int e2b = __builtin_amdgcn_ds_bpermute(permB, qb01);
      int e3a = __builtin_amdgcn_ds_bpermute(permB, qa23);
      int e3b = __builtin_amdgcn_ds_bpermute(permB, qb23);
      uint4 r;
      r.x = (unsigned)(loSel ? e0a : e0b);
      r.y = (unsigned)(loSel ? e1a : e1b);
      r.z = (unsigned)(loSel ? e2a : e2b);
      r.w = (unsigned)(loSel ? e3a : e3b);
      bfr2[kk] = r;
    }

    // ---- stage 2: out (p=0) and skip (p=1,2; only heavy slices) ----
    const int npass = (t0w >= 11776) ? 3 : 1;
#pragma unroll 1
    for (int p = 0; p < npass; ++p) {
      f32x4 acc2[8];
#pragma unroll
      for (int i = 0; i < 8; ++i) acc2[i] = (f32x4){0.f, 0.f, 0.f, 0.f};
#pragma unroll
      for (int kk = 0; kk < 4; ++kk) {
        const unsigned short* wb = wrl + ((p * 4 + kk) << 12) + lhi * 8;
#pragma unroll
        for (int mi = 0; mi < 8; ++mi) {
          uint4 af = *(const uint4*)(wb + (mi * 16 + l15) * 32);
          acc2[mi] = MFMA16(af, bfr2[kk], acc2[mi]);
        }
      }
      if (p == 0) {
        const int tl = t0w + l15;
#pragma unroll
        for (int mi = 0; mi < 8; ++mi) {
          int o0 = mi * 16 + lhi * 4;
#pragma unroll
          for (int r = 0; r < 4; ++r) {
            size_t row = (size_t)(b * 128 + o0 + r);
            out[row * 15872 + tl] = acc2[mi][r] + bres_g[o0 + r]
                                  + x[row * 16384 + 512 + tl];
          }
        }
      } else {
        const int s = t0w + l15 - 11776;
#pragma unroll
        for (int mi = 0; mi < 8; ++mi) {
          int o2 = (p - 1) * 128 + mi * 16 + lhi * 4;
#pragma unroll
          for (int r = 0; r < 4; ++r)
            skipo[(size_t)(b * 256 + o2 + r) * 4096 + s] = acc2[mi][r] + bskip_g[o2 + r];
        }
      }
    }
  }
}

extern "C" void kernel_launch(void* const* d_in, const int* in_sizes, int n_in,
                              void* d_out, int out_size, void* d_ws, size_t ws_size,
                              hipStream_t stream) {
  const float* x      = (const float*)d_in[0];
  const float* w_dil  = (const float*)d_in[1];
  const float* w_res  = (const float*)d_in[2];
  const float* b_res  = (const float*)d_in[3];
  const float* w_skip = (const float*)d_in[4];
  const float* b_skip = (const float*)d_in[5];
  unsigned short* ws16 = (unsigned short*)d_ws;
  float* out = (float*)d_out;
  float* skipo = out + 16252928;  // 8*128*15872

  wn_prep<<<320, 256, 0, stream>>>(w_dil, w_res, w_skip, ws16);

  // 256 persistent blocks (1/CU via 160KB LDS), 8 autonomous waves each
  wn_main<<<256, 512, 163840, stream>>>(x, b_res, b_skip, ws16, out, skipo);
}